// Round 3
// baseline (54.606 us; speedup 1.0000x reference)
//
#include <hip/hip_runtime.h>

// TrainableButterfly: LENGTH=2048 (11 levels), BATCH=4096.
// CROSS_T=1.0, CROSS_PHI=0.0 -> crossings are identity; composing bitrev with
// the per-level gathers gives, in natural storage order:
//   level l = butterfly on slots (s, s + 2^{10-l}), in place; final order = natural.
// Twiddle pair index for storage slot s at level l:
//   p(s,l) = (rev_{10-l}(s & (2^{10-l}-1)) << l) | (s >> (11-l))
//
// Structure (2 rows/block, 256 threads, 3 barriers, 3 LDS round-trips):
//   A:  global load 4 units/row {t,t+256,t+512,t+768} -> levels 0,1 in regs -> LDS
//   S1: levels 2,3,4  (radix-8, complex c = s1 + 64j)
//   S2: levels 5,6,7  (radix-8, complex c = s2 + 8j)
//   F:  read units 4t..4t+3 (complex 8t..8t+7) -> levels 8,9,10 + pointwise -> store
//
// tw layout (float4 index):
//   [0,2048)      TA  ((lvl*2+pj)*2+b)*256 + t   levels 0,1
//   [2048,5120)   S1  2048 + m*256 + t           levels 2,3,4
//   [5120,8192)   S2  5120 + m*256 + t           levels 5,6,7
//   [8192,9216)   E8  8192 + t*4 + i             level 8, lower slot 8t+i
//   [9216,10240)  E9  9216 + t*4 + m             level 9, lower slot 8t+{0,1,4,5}[m]
//   [10240,11264) E10 10240 + w                  level 10, lower slot 2w
//   [11264,12288) PW  11264 + w                  pointwise, complex (2w,2w+1)

__device__ __forceinline__ unsigned revw(unsigned x, int w) {
    return w ? (__brev(x) >> (32 - w)) : 0u;
}
__device__ __forceinline__ unsigned pmap(unsigned slot, int level) {
    int shift = 10 - level;
    return (revw(slot & ((1u << shift) - 1u), shift) << level) | (slot >> (shift + 1));
}

__global__ void twiddle_kernel(const float* __restrict__ phases, float4* __restrict__ tw) {
    int id = blockIdx.x * 256 + threadIdx.x;
    if (id >= 12288) return;
    float t1, t2;
    if (id < 2048) {                         // TA: levels 0,1
        int t = id & 255, r = id >> 8;
        int b = r & 1, pj = (r >> 1) & 1, lvl = r >> 2;
        unsigned unit = (unsigned)t + ((lvl == 0) ? 256u : 512u) * (unsigned)pj;
        unsigned slot = 2u * unit + (unsigned)b;
        unsigned p = pmap(slot, lvl);
        t1 = phases[(lvl * 1024 + p) * 2 + 0];
        t2 = phases[(lvl * 1024 + p) * 2 + 1];
    } else if (id < 8192) {                  // S1/S2 radix-8 tables
        int j2 = id - 2048;
        int sg = j2 / 3072, rem = j2 % 3072;
        int m = rem >> 8, t = rem & 255;
        int L = 2 + 3 * sg;
        int lg = sg ? 3 : 6;
        unsigned H = 1u << lg;
        unsigned s = (((unsigned)t >> lg) << (lg + 3)) | ((unsigned)t & (H - 1));
        int lo = m >> 2, pj = m & 3;
        int j = (lo == 0) ? pj : ((lo == 1) ? ((pj & 1) | ((pj >> 1) << 2)) : (pj << 1));
        unsigned slot = s + (unsigned)j * H;
        int level = L + lo;
        unsigned p = pmap(slot, level);
        t1 = phases[(level * 1024 + p) * 2 + 0];
        t2 = phases[(level * 1024 + p) * 2 + 1];
    } else if (id < 9216) {                  // E8
        int i = id - 8192;
        unsigned slot = 8u * (unsigned)(i >> 2) + (unsigned)(i & 3);
        unsigned p = pmap(slot, 8);
        t1 = phases[(8 * 1024 + p) * 2 + 0];
        t2 = phases[(8 * 1024 + p) * 2 + 1];
    } else if (id < 10240) {                 // E9
        int i = id - 9216;
        int m = i & 3;
        unsigned slot = 8u * (unsigned)(i >> 2) + (unsigned)(((m >> 1) << 2) | (m & 1));
        unsigned p = pmap(slot, 9);
        t1 = phases[(9 * 1024 + p) * 2 + 0];
        t2 = phases[(9 * 1024 + p) * 2 + 1];
    } else if (id < 11264) {                 // E10
        unsigned w = (unsigned)(id - 10240);
        unsigned p = pmap(2u * w, 10);
        t1 = phases[(10 * 1024 + p) * 2 + 0];
        t2 = phases[(10 * 1024 + p) * 2 + 1];
    } else {                                 // PW
        int q = id - 11264;
        t1 = phases[11 * 2048 + q * 2 + 0];
        t2 = phases[11 * 2048 + q * 2 + 1];
    }
    tw[id] = make_float4(cosf(t1), sinf(t1), cosf(t2), sinf(t2));
}

// butterfly: o0 = e^{i t1} v0 + i e^{i t2} v1 ; o1 = i e^{i t1} v0 + e^{i t2} v1
__device__ __forceinline__ void bf(float2 v0, float2 v1, float4 w, float2& o0, float2& o1) {
    float ar = fmaf(w.x, v0.x, -w.y * v0.y);
    float ai = fmaf(w.x, v0.y,  w.y * v0.x);
    float br = fmaf(w.z, v1.x, -w.w * v1.y);
    float bi = fmaf(w.z, v1.y,  w.w * v1.x);
    o0 = make_float2(ar - bi, ai + br);
    o1 = make_float2(br - ai, bi + ar);
}

// Bijective XOR swizzle on float4-unit index: keeps every access pattern of
// A / S1 / S2 / F at the hardware bank floor (checked per 32-lane phase).
__device__ __forceinline__ unsigned swz(unsigned U) {
    return U ^ (((U >> 3) ^ (U >> 6)) & 7u);
}
__device__ __forceinline__ float2 ld2(const float4* l, unsigned c) {
    return ((const float2*)l)[swz(c >> 1) * 2 + (c & 1)];
}
__device__ __forceinline__ void st2(float4* l, unsigned c, float2 v) {
    ((float2*)l)[swz(c >> 1) * 2 + (c & 1)] = v;
}

// three level patterns on 8 elements (pairs at reg-stride 4, 2, 1)
__device__ __forceinline__ void lvlA(float2 e[8], const float4 w[4]) {
    bf(e[0], e[4], w[0], e[0], e[4]);
    bf(e[1], e[5], w[1], e[1], e[5]);
    bf(e[2], e[6], w[2], e[2], e[6]);
    bf(e[3], e[7], w[3], e[3], e[7]);
}
__device__ __forceinline__ void lvlB(float2 e[8], const float4 w[4]) {
    bf(e[0], e[2], w[0], e[0], e[2]);
    bf(e[1], e[3], w[1], e[1], e[3]);
    bf(e[4], e[6], w[2], e[4], e[6]);
    bf(e[5], e[7], w[3], e[5], e[7]);
}
__device__ __forceinline__ void lvlC(float2 e[8], const float4 w[4]) {
    bf(e[0], e[1], w[0], e[0], e[1]);
    bf(e[2], e[3], w[1], e[2], e[3]);
    bf(e[4], e[5], w[2], e[4], e[5]);
    bf(e[6], e[7], w[3], e[6], e[7]);
}

template <int SG>  // SG=0: levels 2,3,4 (H=64); SG=1: levels 5,6,7 (H=8)
__device__ __forceinline__ void sstage(float4* l0, float4* l1,
                                       const float4* __restrict__ tw, unsigned t) {
    constexpr unsigned LG = SG ? 3u : 6u;
    constexpr unsigned H = 1u << LG;
    constexpr int base = SG ? 5120 : 2048;
    const unsigned s = ((t >> LG) << (LG + 3)) | (t & (H - 1));
    float2 e0[8], e1[8];
#pragma unroll
    for (int j = 0; j < 8; ++j) e0[j] = ld2(l0, s + H * j);
#pragma unroll
    for (int j = 0; j < 8; ++j) e1[j] = ld2(l1, s + H * j);
    float4 w[4];
#pragma unroll
    for (int k = 0; k < 4; ++k) w[k] = tw[base + k * 256 + t];
    lvlA(e0, w); lvlA(e1, w);
#pragma unroll
    for (int k = 0; k < 4; ++k) w[k] = tw[base + (4 + k) * 256 + t];
    lvlB(e0, w); lvlB(e1, w);
#pragma unroll
    for (int k = 0; k < 4; ++k) w[k] = tw[base + (8 + k) * 256 + t];
    lvlC(e0, w); lvlC(e1, w);
#pragma unroll
    for (int j = 0; j < 8; ++j) st2(l0, s + H * j, e0[j]);
#pragma unroll
    for (int j = 0; j < 8; ++j) st2(l1, s + H * j, e1[j]);
}

__global__ __launch_bounds__(256, 5) void bfly_kernel(const float4* __restrict__ x,
                                                      const float4* __restrict__ tw,
                                                      float4* __restrict__ out) {
    __shared__ float4 lds[2048];   // 2 rows x 1024 units = 32 KB
    const unsigned t = threadIdx.x;
    const int rowbase = blockIdx.x * 2048;
    float4* l0 = lds;
    float4* l1 = lds + 1024;

    // ---- A: levels 0,1 (units t, t+256, t+512, t+768; z[2k+b] = slot 2(t+256k)+b) ----
    {
        const float4* x0 = x + rowbase;
        const float4* x1 = x + rowbase + 1024;
        float2 z0[8], z1[8];
#pragma unroll
        for (int k = 0; k < 4; ++k) {
            float4 u = x0[t + 256u * k];
            z0[2 * k] = make_float2(u.x, u.y); z0[2 * k + 1] = make_float2(u.z, u.w);
        }
#pragma unroll
        for (int k = 0; k < 4; ++k) {
            float4 u = x1[t + 256u * k];
            z1[2 * k] = make_float2(u.x, u.y); z1[2 * k + 1] = make_float2(u.z, u.w);
        }
        float4 w[4];
#pragma unroll
        for (int k = 0; k < 4; ++k) w[k] = tw[k * 256 + t];   // level 0
        lvlA(z0, w); lvlA(z1, w);
#pragma unroll
        for (int k = 0; k < 4; ++k) w[k] = tw[(4 + k) * 256 + t];  // level 1
        lvlB(z0, w); lvlB(z1, w);
#pragma unroll
        for (int k = 0; k < 4; ++k) {
            l0[swz(t + 256u * k)] = make_float4(z0[2 * k].x, z0[2 * k].y, z0[2 * k + 1].x, z0[2 * k + 1].y);
            l1[swz(t + 256u * k)] = make_float4(z1[2 * k].x, z1[2 * k].y, z1[2 * k + 1].x, z1[2 * k + 1].y);
        }
    }
    __syncthreads();

    sstage<0>(l0, l1, tw, t);   // levels 2,3,4
    __syncthreads();
    sstage<1>(l0, l1, tw, t);   // levels 5,6,7
    __syncthreads();

    // ---- F: levels 8,9,10 + pointwise (units 4t..4t+3; z[i] = slot 8t+i) ----
    {
        float2 z0[8], z1[8];
#pragma unroll
        for (int k = 0; k < 4; ++k) {
            float4 u = l0[swz(4u * t + k)];
            z0[2 * k] = make_float2(u.x, u.y); z0[2 * k + 1] = make_float2(u.z, u.w);
            u = l1[swz(4u * t + k)];
            z1[2 * k] = make_float2(u.x, u.y); z1[2 * k + 1] = make_float2(u.z, u.w);
        }
        float4 w[4];
#pragma unroll
        for (int i = 0; i < 4; ++i) w[i] = tw[8192 + 4u * t + i];   // level 8
        lvlA(z0, w); lvlA(z1, w);
#pragma unroll
        for (int i = 0; i < 4; ++i) w[i] = tw[9216 + 4u * t + i];   // level 9
        lvlB(z0, w); lvlB(z1, w);
#pragma unroll
        for (int i = 0; i < 4; ++i) w[i] = tw[10240 + 4u * t + i];  // level 10
        lvlC(z0, w); lvlC(z1, w);
#pragma unroll
        for (int k = 0; k < 4; ++k) {
            float4 p = tw[11264 + 4u * t + k];
            out[rowbase + 4u * t + k] = make_float4(
                fmaf(p.x, z0[2 * k].x, -p.y * z0[2 * k].y),
                fmaf(p.x, z0[2 * k].y,  p.y * z0[2 * k].x),
                fmaf(p.z, z0[2 * k + 1].x, -p.w * z0[2 * k + 1].y),
                fmaf(p.z, z0[2 * k + 1].y,  p.w * z0[2 * k + 1].x));
            out[rowbase + 1024 + 4u * t + k] = make_float4(
                fmaf(p.x, z1[2 * k].x, -p.y * z1[2 * k].y),
                fmaf(p.x, z1[2 * k].y,  p.y * z1[2 * k].x),
                fmaf(p.z, z1[2 * k + 1].x, -p.w * z1[2 * k + 1].y),
                fmaf(p.z, z1[2 * k + 1].y,  p.w * z1[2 * k + 1].x));
        }
    }
}

extern "C" void kernel_launch(void* const* d_in, const int* in_sizes, int n_in,
                              void* d_out, int out_size, void* d_ws, size_t ws_size,
                              hipStream_t stream) {
    const float* x = (const float*)d_in[0];        // (4096, 2048, 2) f32
    const float* phases = (const float*)d_in[1];   // (12, 1024, 2) f32
    float4* tw = (float4*)d_ws;                    // 192 KB

    twiddle_kernel<<<48, 256, 0, stream>>>(phases, tw);
    bfly_kernel<<<2048, 256, 0, stream>>>((const float4*)x, tw, (float4*)d_out);
}

// Round 4
// 42.470 us; speedup vs baseline: 1.2858x; 1.2858x over previous
//
#include <hip/hip_runtime.h>

// TrainableButterfly: LENGTH=2048 (11 levels), BATCH=4096.
// CROSS_T=1.0, CROSS_PHI=0.0 -> crossings are identity; in natural storage order
// level l = butterfly on slots (s, s + 2^{10-l}), in place; final order natural.
// Pair-twiddle index for lower slot s at level l:
//   p(s,l) = (rev_{10-l}(s & (2^{10-l}-1)) << l) | (s >> (11-l))
//
// Structure (2 rows/block, 256 threads, 3 barriers, plain linear LDS):
//   A:  load units {t,t+256,t+512,t+768} -> levels 0,1 in regs -> LDS
//   S1: levels 2,3,4 (radix-8, c = s1 + 64j)
//   S2: levels 5,6,7 (radix-8, c = s2 + 8j)
//   F:  read unit u=t+256g; level 8 via shfl_xor(2), level 9 via shfl_xor(1)
//       (product-exchange form), level 10 in-reg, pointwise, coalesced store.
//
// tw float4 layout:
//   [0,2048)      TA  ((lvl*2+pj)*2+b)*256+t   levels 0,1
//   [2048,5120)   S1  2048+m*256+t             levels 2,3,4
//   [5120,8192)   S2  5120+m*256+t             levels 5,6,7
//   [8192,9216)   E8  8192+u : (cos/sin theta(2u), cos/sin theta(2u+1)), lvl 8
//                    theta(c) = phases[8][p(c&~4,8)][(c>>2)&1]
//   [9216,10240)  E9  9216+u : same with mask ~2, bit (c>>1)&1, lvl 9
//   [10240,11264) E10 10240+u : full pair twiddle, lower slot 2u, lvl 10
//   [11264,12288) PW  11264+u : pointwise for complexes (2u, 2u+1)

__device__ __forceinline__ unsigned revw(unsigned x, int w) {
    return w ? (__brev(x) >> (32 - w)) : 0u;
}
__device__ __forceinline__ unsigned pmap(unsigned slot, int level) {
    int shift = 10 - level;
    return (revw(slot & ((1u << shift) - 1u), shift) << level) | (slot >> (shift + 1));
}

__global__ void twiddle_kernel(const float* __restrict__ phases, float4* __restrict__ tw) {
    int id = blockIdx.x * 256 + threadIdx.x;
    if (id >= 12288) return;
    float t1, t2;
    if (id < 2048) {                         // TA: levels 0,1
        int t = id & 255, r = id >> 8;
        int b = r & 1, pj = (r >> 1) & 1, lvl = r >> 2;
        unsigned unit = (unsigned)t + ((lvl == 0) ? 256u : 512u) * (unsigned)pj;
        unsigned slot = 2u * unit + (unsigned)b;
        unsigned p = pmap(slot, lvl);
        t1 = phases[(lvl * 1024 + p) * 2 + 0];
        t2 = phases[(lvl * 1024 + p) * 2 + 1];
    } else if (id < 8192) {                  // S1/S2 radix-8 tables
        int j2 = id - 2048;
        int sg = j2 / 3072, rem = j2 % 3072;
        int m = rem >> 8, t = rem & 255;
        int L = 2 + 3 * sg;
        int lg = sg ? 3 : 6;
        unsigned H = 1u << lg;
        unsigned s = (((unsigned)t >> lg) << (lg + 3)) | ((unsigned)t & (H - 1));
        int lo = m >> 2, pj = m & 3;
        int j = (lo == 0) ? pj : ((lo == 1) ? ((pj & 1) | ((pj >> 1) << 2)) : (pj << 1));
        unsigned slot = s + (unsigned)j * H;
        int level = L + lo;
        unsigned p = pmap(slot, level);
        t1 = phases[(level * 1024 + p) * 2 + 0];
        t2 = phases[(level * 1024 + p) * 2 + 1];
    } else if (id < 9216) {                  // E8 (per-unit, side-baked theta)
        unsigned u = (unsigned)(id - 8192);
        unsigned c0 = 2u * u, c1 = 2u * u + 1u;
        t1 = phases[(8 * 1024 + pmap(c0 & ~4u, 8)) * 2 + ((c0 >> 2) & 1)];
        t2 = phases[(8 * 1024 + pmap(c1 & ~4u, 8)) * 2 + ((c1 >> 2) & 1)];
    } else if (id < 10240) {                 // E9
        unsigned u = (unsigned)(id - 9216);
        unsigned c0 = 2u * u, c1 = 2u * u + 1u;
        t1 = phases[(9 * 1024 + pmap(c0 & ~2u, 9)) * 2 + ((c0 >> 1) & 1)];
        t2 = phases[(9 * 1024 + pmap(c1 & ~2u, 9)) * 2 + ((c1 >> 1) & 1)];
    } else if (id < 11264) {                 // E10: full pair twiddle, lower slot 2u
        unsigned u = (unsigned)(id - 10240);
        unsigned p = pmap(2u * u, 10);
        t1 = phases[(10 * 1024 + p) * 2 + 0];
        t2 = phases[(10 * 1024 + p) * 2 + 1];
    } else {                                 // PW
        int q = id - 11264;
        t1 = phases[11 * 2048 + q * 2 + 0];
        t2 = phases[11 * 2048 + q * 2 + 1];
    }
    tw[id] = make_float4(cosf(t1), sinf(t1), cosf(t2), sinf(t2));
}

// butterfly: o0 = e^{i t1} v0 + i e^{i t2} v1 ; o1 = i e^{i t1} v0 + e^{i t2} v1
__device__ __forceinline__ void bf(float2 v0, float2 v1, float4 w, float2& o0, float2& o1) {
    float ar = fmaf(w.x, v0.x, -w.y * v0.y);
    float ai = fmaf(w.x, v0.y,  w.y * v0.x);
    float br = fmaf(w.z, v1.x, -w.w * v1.y);
    float bi = fmaf(w.z, v1.y,  w.w * v1.x);
    o0 = make_float2(ar - bi, ai + br);
    o1 = make_float2(br - ai, bi + ar);
}
// complex product e^{i theta} * z, theta given by (wc,ws)
__device__ __forceinline__ float2 cm(float wc, float ws, float2 z) {
    return make_float2(fmaf(wc, z.x, -ws * z.y), fmaf(wc, z.y, ws * z.x));
}
// both sides of an exchanged butterfly: o = local + i * recv
__device__ __forceinline__ float2 comb(float2 local, float2 recv) {
    return make_float2(local.x - recv.y, local.y + recv.x);
}
__device__ __forceinline__ float2 sx(float2 v, int mask) {
    return make_float2(__shfl_xor(v.x, mask, 64), __shfl_xor(v.y, mask, 64));
}

// level patterns on 8 complexes (pairs at reg-stride 4, 2, 1)
__device__ __forceinline__ void lvlA(float2 e[8], const float4 w[4]) {
    bf(e[0], e[4], w[0], e[0], e[4]);
    bf(e[1], e[5], w[1], e[1], e[5]);
    bf(e[2], e[6], w[2], e[2], e[6]);
    bf(e[3], e[7], w[3], e[3], e[7]);
}
__device__ __forceinline__ void lvlB(float2 e[8], const float4 w[4]) {
    bf(e[0], e[2], w[0], e[0], e[2]);
    bf(e[1], e[3], w[1], e[1], e[3]);
    bf(e[4], e[6], w[2], e[4], e[6]);
    bf(e[5], e[7], w[3], e[5], e[7]);
}
__device__ __forceinline__ void lvlC(float2 e[8], const float4 w[4]) {
    bf(e[0], e[1], w[0], e[0], e[1]);
    bf(e[2], e[3], w[1], e[2], e[3]);
    bf(e[4], e[5], w[2], e[4], e[5]);
    bf(e[6], e[7], w[3], e[6], e[7]);
}

__global__ __launch_bounds__(256, 4) void bfly_kernel(const float4* __restrict__ x,
                                                      const float4* __restrict__ tw,
                                                      float4* __restrict__ out) {
    __shared__ float4 lds[2048];          // 2 rows x 1024 units, plain linear
    float2* lf = (float2*)lds;            // row r complex c at lf[r*2048 + c]
    const unsigned t = threadIdx.x;
    const int rowbase = blockIdx.x * 2048;

    float2 z0[8], z1[8];
    float4 w[4], wn[4];

    // ---- A: levels 0,1 on units {t+256k}; z[2k+b] = complex 2(t+256k)+b ----
    {
        const float4* x0 = x + rowbase;
        const float4* x1 = x + rowbase + 1024;
#pragma unroll
        for (int k = 0; k < 4; ++k) {
            float4 u = x0[t + 256u * k];
            z0[2 * k] = make_float2(u.x, u.y); z0[2 * k + 1] = make_float2(u.z, u.w);
        }
#pragma unroll
        for (int k = 0; k < 4; ++k) {
            float4 u = x1[t + 256u * k];
            z1[2 * k] = make_float2(u.x, u.y); z1[2 * k + 1] = make_float2(u.z, u.w);
        }
#pragma unroll
        for (int k = 0; k < 4; ++k) w[k] = tw[k * 256 + t];        // level 0
        lvlA(z0, w); lvlA(z1, w);
#pragma unroll
        for (int k = 0; k < 4; ++k) w[k] = tw[(4 + k) * 256 + t];  // level 1
        lvlB(z0, w); lvlB(z1, w);
#pragma unroll
        for (int m = 0; m < 4; ++m) wn[m] = tw[2048 + m * 256 + t];  // prefetch S1.A
#pragma unroll
        for (int k = 0; k < 4; ++k) {
            lds[t + 256u * k]        = make_float4(z0[2 * k].x, z0[2 * k].y, z0[2 * k + 1].x, z0[2 * k + 1].y);
            lds[1024 + t + 256u * k] = make_float4(z1[2 * k].x, z1[2 * k].y, z1[2 * k + 1].x, z1[2 * k + 1].y);
        }
    }
    __syncthreads();

    // ---- S1: levels 2,3,4 (c = s + 64j) ----
    {
        const unsigned s = ((t >> 6) << 9) | (t & 63u);
        float4 wb[4], wc[4];
#pragma unroll
        for (int j = 0; j < 8; ++j) z0[j] = lf[s + 64u * j];
#pragma unroll
        for (int j = 0; j < 8; ++j) z1[j] = lf[2048 + s + 64u * j];
#pragma unroll
        for (int m = 0; m < 4; ++m) wb[m] = tw[2048 + (4 + m) * 256 + t];
#pragma unroll
        for (int m = 0; m < 4; ++m) wc[m] = tw[2048 + (8 + m) * 256 + t];
        lvlA(z0, wn); lvlA(z1, wn);
        lvlB(z0, wb); lvlB(z1, wb);
        lvlC(z0, wc); lvlC(z1, wc);
#pragma unroll
        for (int m = 0; m < 4; ++m) wn[m] = tw[5120 + m * 256 + t];  // prefetch S2.A
#pragma unroll
        for (int j = 0; j < 8; ++j) lf[s + 64u * j] = z0[j];
#pragma unroll
        for (int j = 0; j < 8; ++j) lf[2048 + s + 64u * j] = z1[j];
    }
    __syncthreads();

    // ---- S2: levels 5,6,7 (c = s2 + 8j) ----
    {
        const unsigned s2 = ((t >> 3) << 6) | (t & 7u);
        float4 wb[4], wc[4];
#pragma unroll
        for (int j = 0; j < 8; ++j) z0[j] = lf[s2 + 8u * j];
#pragma unroll
        for (int j = 0; j < 8; ++j) z1[j] = lf[2048 + s2 + 8u * j];
#pragma unroll
        for (int m = 0; m < 4; ++m) wb[m] = tw[5120 + (4 + m) * 256 + t];
#pragma unroll
        for (int m = 0; m < 4; ++m) wc[m] = tw[5120 + (8 + m) * 256 + t];
        lvlA(z0, wn); lvlA(z1, wn);
        lvlB(z0, wb); lvlB(z1, wb);
        lvlC(z0, wc); lvlC(z1, wc);
#pragma unroll
        for (int g = 0; g < 4; ++g) wn[g] = tw[8192 + t + 256u * g];  // prefetch E8
#pragma unroll
        for (int j = 0; j < 8; ++j) lf[s2 + 8u * j] = z0[j];
#pragma unroll
        for (int j = 0; j < 8; ++j) lf[2048 + s2 + 8u * j] = z1[j];
    }
    __syncthreads();

    // ---- F: levels 8 (shfl^2), 9 (shfl^1), 10 (in-reg) + pointwise + store ----
#pragma unroll
    for (int g = 0; g < 4; ++g) {
        const unsigned u = t + 256u * g;
        float4 q0 = lds[u];
        float4 q1 = lds[1024 + u];
        float4 w9 = tw[9216 + u];
        float4 wA = tw[10240 + u];
        float4 p  = tw[11264 + u];
        float2 x00 = make_float2(q0.x, q0.y), x01 = make_float2(q0.z, q0.w);
        float2 x10 = make_float2(q1.x, q1.y), x11 = make_float2(q1.z, q1.w);
        // level 8: partner lane t^2
        float4 w8 = wn[g];
        float2 a00 = cm(w8.x, w8.y, x00), a01 = cm(w8.z, w8.w, x01);
        float2 a10 = cm(w8.x, w8.y, x10), a11 = cm(w8.z, w8.w, x11);
        x00 = comb(a00, sx(a00, 2)); x01 = comb(a01, sx(a01, 2));
        x10 = comb(a10, sx(a10, 2)); x11 = comb(a11, sx(a11, 2));
        // level 9: partner lane t^1
        a00 = cm(w9.x, w9.y, x00); a01 = cm(w9.z, w9.w, x01);
        a10 = cm(w9.x, w9.y, x10); a11 = cm(w9.z, w9.w, x11);
        x00 = comb(a00, sx(a00, 1)); x01 = comb(a01, sx(a01, 1));
        x10 = comb(a10, sx(a10, 1)); x11 = comb(a11, sx(a11, 1));
        // level 10: intra-unit pair (2u, 2u+1)
        bf(x00, x01, wA, x00, x01);
        bf(x10, x11, wA, x10, x11);
        // pointwise + coalesced store
        out[rowbase + u] = make_float4(
            fmaf(p.x, x00.x, -p.y * x00.y), fmaf(p.x, x00.y, p.y * x00.x),
            fmaf(p.z, x01.x, -p.w * x01.y), fmaf(p.z, x01.y, p.w * x01.x));
        out[rowbase + 1024 + u] = make_float4(
            fmaf(p.x, x10.x, -p.y * x10.y), fmaf(p.x, x10.y, p.y * x10.x),
            fmaf(p.z, x11.x, -p.w * x11.y), fmaf(p.z, x11.y, p.w * x11.x));
    }
}

extern "C" void kernel_launch(void* const* d_in, const int* in_sizes, int n_in,
                              void* d_out, int out_size, void* d_ws, size_t ws_size,
                              hipStream_t stream) {
    const float* x = (const float*)d_in[0];        // (4096, 2048, 2) f32
    const float* phases = (const float*)d_in[1];   // (12, 1024, 2) f32
    float4* tw = (float4*)d_ws;                    // 192 KB

    twiddle_kernel<<<48, 256, 0, stream>>>(phases, tw);
    bfly_kernel<<<2048, 256, 0, stream>>>((const float4*)x, tw, (float4*)d_out);
}

// Round 5
// 42.407 us; speedup vs baseline: 1.2877x; 1.0015x over previous
//
#include <hip/hip_runtime.h>

// TrainableButterfly: LENGTH=2048 (11 levels), BATCH=4096.
// CROSS_T=1.0, CROSS_PHI=0.0 -> crossings are identity; in natural storage order
// level l = butterfly on slots (s, s + 2^{10-l}), in place; final order natural.
// Pair-twiddle index for lower slot s at level l:
//   p(s,l) = (rev_{10-l}(s & (2^{10-l}-1)) << l) | (s >> (11-l))
//
// Structure (2 rows/block, 256 threads, 3 RAW barriers, plain linear LDS):
//   A:  load units {t,t+256,t+512,t+768} -> levels 0,1 in regs -> LDS
//   S1: levels 2,3,4 (radix-8, c = s1 + 64j)
//   S2: levels 5,6,7 (radix-8, c = s2 + 8j)
//   F:  read unit u=t+256g; level 8 via shfl_xor(2), level 9 via shfl_xor(1)
//       (product-exchange form), level 10 in-reg, pointwise, coalesced store.
// Barriers are raw s_barrier preceded by lgkmcnt(0) only -> twiddle prefetch
// loads (vmcnt) stay in flight across barriers (T4: never drain vmcnt at bar).

__device__ __forceinline__ unsigned revw(unsigned x, int w) {
    return w ? (__brev(x) >> (32 - w)) : 0u;
}
__device__ __forceinline__ unsigned pmap(unsigned slot, int level) {
    int shift = 10 - level;
    return (revw(slot & ((1u << shift) - 1u), shift) << level) | (slot >> (shift + 1));
}

__global__ void twiddle_kernel(const float* __restrict__ phases, float4* __restrict__ tw) {
    int id = blockIdx.x * 256 + threadIdx.x;
    if (id >= 12288) return;
    float t1, t2;
    if (id < 2048) {                         // TA: levels 0,1
        int t = id & 255, r = id >> 8;
        int b = r & 1, pj = (r >> 1) & 1, lvl = r >> 2;
        unsigned unit = (unsigned)t + ((lvl == 0) ? 256u : 512u) * (unsigned)pj;
        unsigned slot = 2u * unit + (unsigned)b;
        unsigned p = pmap(slot, lvl);
        t1 = phases[(lvl * 1024 + p) * 2 + 0];
        t2 = phases[(lvl * 1024 + p) * 2 + 1];
    } else if (id < 8192) {                  // S1/S2 radix-8 tables
        int j2 = id - 2048;
        int sg = j2 / 3072, rem = j2 % 3072;
        int m = rem >> 8, t = rem & 255;
        int L = 2 + 3 * sg;
        int lg = sg ? 3 : 6;
        unsigned H = 1u << lg;
        unsigned s = (((unsigned)t >> lg) << (lg + 3)) | ((unsigned)t & (H - 1));
        int lo = m >> 2, pj = m & 3;
        int j = (lo == 0) ? pj : ((lo == 1) ? ((pj & 1) | ((pj >> 1) << 2)) : (pj << 1));
        unsigned slot = s + (unsigned)j * H;
        int level = L + lo;
        unsigned p = pmap(slot, level);
        t1 = phases[(level * 1024 + p) * 2 + 0];
        t2 = phases[(level * 1024 + p) * 2 + 1];
    } else if (id < 9216) {                  // E8 (per-unit, side-baked theta)
        unsigned u = (unsigned)(id - 8192);
        unsigned c0 = 2u * u, c1 = 2u * u + 1u;
        t1 = phases[(8 * 1024 + pmap(c0 & ~4u, 8)) * 2 + ((c0 >> 2) & 1)];
        t2 = phases[(8 * 1024 + pmap(c1 & ~4u, 8)) * 2 + ((c1 >> 2) & 1)];
    } else if (id < 10240) {                 // E9
        unsigned u = (unsigned)(id - 9216);
        unsigned c0 = 2u * u, c1 = 2u * u + 1u;
        t1 = phases[(9 * 1024 + pmap(c0 & ~2u, 9)) * 2 + ((c0 >> 1) & 1)];
        t2 = phases[(9 * 1024 + pmap(c1 & ~2u, 9)) * 2 + ((c1 >> 1) & 1)];
    } else if (id < 11264) {                 // E10: full pair twiddle, lower slot 2u
        unsigned u = (unsigned)(id - 10240);
        unsigned p = pmap(2u * u, 10);
        t1 = phases[(10 * 1024 + p) * 2 + 0];
        t2 = phases[(10 * 1024 + p) * 2 + 1];
    } else {                                 // PW
        int q = id - 11264;
        t1 = phases[11 * 2048 + q * 2 + 0];
        t2 = phases[11 * 2048 + q * 2 + 1];
    }
    tw[id] = make_float4(cosf(t1), sinf(t1), cosf(t2), sinf(t2));
}

// butterfly: o0 = e^{i t1} v0 + i e^{i t2} v1 ; o1 = i e^{i t1} v0 + e^{i t2} v1
__device__ __forceinline__ void bf(float2 v0, float2 v1, float4 w, float2& o0, float2& o1) {
    float ar = fmaf(w.x, v0.x, -w.y * v0.y);
    float ai = fmaf(w.x, v0.y,  w.y * v0.x);
    float br = fmaf(w.z, v1.x, -w.w * v1.y);
    float bi = fmaf(w.z, v1.y,  w.w * v1.x);
    o0 = make_float2(ar - bi, ai + br);
    o1 = make_float2(br - ai, bi + ar);
}
__device__ __forceinline__ float2 cm(float wc, float ws, float2 z) {
    return make_float2(fmaf(wc, z.x, -ws * z.y), fmaf(wc, z.y, ws * z.x));
}
__device__ __forceinline__ float2 comb(float2 local, float2 recv) {
    return make_float2(local.x - recv.y, local.y + recv.x);
}
__device__ __forceinline__ float2 sx(float2 v, int mask) {
    return make_float2(__shfl_xor(v.x, mask, 64), __shfl_xor(v.y, mask, 64));
}

// level patterns on 8 complexes (pairs at reg-stride 4, 2, 1)
__device__ __forceinline__ void lvlA(float2 e[8], const float4 w[4]) {
    bf(e[0], e[4], w[0], e[0], e[4]);
    bf(e[1], e[5], w[1], e[1], e[5]);
    bf(e[2], e[6], w[2], e[2], e[6]);
    bf(e[3], e[7], w[3], e[3], e[7]);
}
__device__ __forceinline__ void lvlB(float2 e[8], const float4 w[4]) {
    bf(e[0], e[2], w[0], e[0], e[2]);
    bf(e[1], e[3], w[1], e[1], e[3]);
    bf(e[4], e[6], w[2], e[4], e[6]);
    bf(e[5], e[7], w[3], e[5], e[7]);
}
__device__ __forceinline__ void lvlC(float2 e[8], const float4 w[4]) {
    bf(e[0], e[1], w[0], e[0], e[1]);
    bf(e[2], e[3], w[1], e[2], e[3]);
    bf(e[4], e[5], w[2], e[4], e[5]);
    bf(e[6], e[7], w[3], e[6], e[7]);
}

// Raw barrier: make LDS writes visible, do NOT drain vmcnt (twiddle prefetch
// stays in flight across the barrier — T4).
__device__ __forceinline__ void lbar() {
    asm volatile("s_waitcnt lgkmcnt(0)" ::: "memory");
    __builtin_amdgcn_s_barrier();
}

__global__ __launch_bounds__(256, 4) void bfly_kernel(const float4* __restrict__ x,
                                                      const float4* __restrict__ tw,
                                                      float4* __restrict__ out) {
    __shared__ float4 lds[2048];          // 2 rows x 1024 units, plain linear
    float2* lf = (float2*)lds;            // row r complex c at lf[r*2048 + c]
    const unsigned t = threadIdx.x;
    const int rowbase = blockIdx.x * 2048;

    float2 z0[8], z1[8];
    float4 w[4], wn[4];

    // ---- A: levels 0,1 on units {t+256k}; z[2k+b] = complex 2(t+256k)+b ----
    {
        const float4* x0 = x + rowbase;
        const float4* x1 = x + rowbase + 1024;
#pragma unroll
        for (int k = 0; k < 4; ++k) {
            float4 u = x0[t + 256u * k];
            z0[2 * k] = make_float2(u.x, u.y); z0[2 * k + 1] = make_float2(u.z, u.w);
        }
#pragma unroll
        for (int k = 0; k < 4; ++k) {
            float4 u = x1[t + 256u * k];
            z1[2 * k] = make_float2(u.x, u.y); z1[2 * k + 1] = make_float2(u.z, u.w);
        }
#pragma unroll
        for (int k = 0; k < 4; ++k) w[k] = tw[k * 256 + t];        // level 0
        lvlA(z0, w); lvlA(z1, w);
#pragma unroll
        for (int k = 0; k < 4; ++k) w[k] = tw[(4 + k) * 256 + t];  // level 1
        lvlB(z0, w); lvlB(z1, w);
#pragma unroll
        for (int m = 0; m < 4; ++m) wn[m] = tw[2048 + m * 256 + t];  // prefetch S1.A
#pragma unroll
        for (int k = 0; k < 4; ++k) {
            lds[t + 256u * k]        = make_float4(z0[2 * k].x, z0[2 * k].y, z0[2 * k + 1].x, z0[2 * k + 1].y);
            lds[1024 + t + 256u * k] = make_float4(z1[2 * k].x, z1[2 * k].y, z1[2 * k + 1].x, z1[2 * k + 1].y);
        }
    }
    lbar();

    // ---- S1: levels 2,3,4 (c = s + 64j) ----
    {
        const unsigned s = ((t >> 6) << 9) | (t & 63u);
        float4 wb[4], wc[4];
#pragma unroll
        for (int m = 0; m < 4; ++m) wb[m] = tw[2048 + (4 + m) * 256 + t];
#pragma unroll
        for (int m = 0; m < 4; ++m) wc[m] = tw[2048 + (8 + m) * 256 + t];
#pragma unroll
        for (int j = 0; j < 8; ++j) z0[j] = lf[s + 64u * j];
#pragma unroll
        for (int j = 0; j < 8; ++j) z1[j] = lf[2048 + s + 64u * j];
        lvlA(z0, wn); lvlA(z1, wn);
        lvlB(z0, wb); lvlB(z1, wb);
        lvlC(z0, wc); lvlC(z1, wc);
#pragma unroll
        for (int m = 0; m < 4; ++m) wn[m] = tw[5120 + m * 256 + t];  // prefetch S2.A
#pragma unroll
        for (int j = 0; j < 8; ++j) lf[s + 64u * j] = z0[j];
#pragma unroll
        for (int j = 0; j < 8; ++j) lf[2048 + s + 64u * j] = z1[j];
    }
    lbar();

    // ---- S2: levels 5,6,7 (c = s2 + 8j) ----
    {
        const unsigned s2 = ((t >> 3) << 6) | (t & 7u);
        float4 wb[4], wc[4];
#pragma unroll
        for (int m = 0; m < 4; ++m) wb[m] = tw[5120 + (4 + m) * 256 + t];
#pragma unroll
        for (int m = 0; m < 4; ++m) wc[m] = tw[5120 + (8 + m) * 256 + t];
#pragma unroll
        for (int j = 0; j < 8; ++j) z0[j] = lf[s2 + 8u * j];
#pragma unroll
        for (int j = 0; j < 8; ++j) z1[j] = lf[2048 + s2 + 8u * j];
        lvlA(z0, wn); lvlA(z1, wn);
        lvlB(z0, wb); lvlB(z1, wb);
        lvlC(z0, wc); lvlC(z1, wc);
#pragma unroll
        for (int g = 0; g < 4; ++g) wn[g] = tw[8192 + t + 256u * g];  // prefetch E8
#pragma unroll
        for (int j = 0; j < 8; ++j) lf[s2 + 8u * j] = z0[j];
#pragma unroll
        for (int j = 0; j < 8; ++j) lf[2048 + s2 + 8u * j] = z1[j];
    }
    lbar();

    // ---- F: levels 8 (shfl^2), 9 (shfl^1), 10 (in-reg) + pointwise + store ----
#pragma unroll
    for (int g = 0; g < 4; ++g) {
        const unsigned u = t + 256u * g;
        float4 w9 = tw[9216 + u];
        float4 wA = tw[10240 + u];
        float4 p  = tw[11264 + u];
        float4 q0 = lds[u];
        float4 q1 = lds[1024 + u];
        float2 x00 = make_float2(q0.x, q0.y), x01 = make_float2(q0.z, q0.w);
        float2 x10 = make_float2(q1.x, q1.y), x11 = make_float2(q1.z, q1.w);
        // level 8: partner lane t^2
        float4 w8 = wn[g];
        float2 a00 = cm(w8.x, w8.y, x00), a01 = cm(w8.z, w8.w, x01);
        float2 a10 = cm(w8.x, w8.y, x10), a11 = cm(w8.z, w8.w, x11);
        x00 = comb(a00, sx(a00, 2)); x01 = comb(a01, sx(a01, 2));
        x10 = comb(a10, sx(a10, 2)); x11 = comb(a11, sx(a11, 2));
        // level 9: partner lane t^1
        a00 = cm(w9.x, w9.y, x00); a01 = cm(w9.z, w9.w, x01);
        a10 = cm(w9.x, w9.y, x10); a11 = cm(w9.z, w9.w, x11);
        x00 = comb(a00, sx(a00, 1)); x01 = comb(a01, sx(a01, 1));
        x10 = comb(a10, sx(a10, 1)); x11 = comb(a11, sx(a11, 1));
        // level 10: intra-unit pair (2u, 2u+1)
        bf(x00, x01, wA, x00, x01);
        bf(x10, x11, wA, x10, x11);
        // pointwise + coalesced store
        out[rowbase + u] = make_float4(
            fmaf(p.x, x00.x, -p.y * x00.y), fmaf(p.x, x00.y, p.y * x00.x),
            fmaf(p.z, x01.x, -p.w * x01.y), fmaf(p.z, x01.y, p.w * x01.x));
        out[rowbase + 1024 + u] = make_float4(
            fmaf(p.x, x10.x, -p.y * x10.y), fmaf(p.x, x10.y, p.y * x10.x),
            fmaf(p.z, x11.x, -p.w * x11.y), fmaf(p.z, x11.y, p.w * x11.x));
    }
}

extern "C" void kernel_launch(void* const* d_in, const int* in_sizes, int n_in,
                              void* d_out, int out_size, void* d_ws, size_t ws_size,
                              hipStream_t stream) {
    const float* x = (const float*)d_in[0];        // (4096, 2048, 2) f32
    const float* phases = (const float*)d_in[1];   // (12, 1024, 2) f32
    float4* tw = (float4*)d_ws;                    // 192 KB

    twiddle_kernel<<<48, 256, 0, stream>>>(phases, tw);
    bfly_kernel<<<2048, 256, 0, stream>>>((const float4*)x, tw, (float4*)d_out);
}